// Round 1
// baseline (582.144 us; speedup 1.0000x reference)
//
#include <hip/hip_runtime.h>
#include <hip/hip_bf16.h>

#define D 64
#define P 20            // NUM_PROTO
#define ROWS_PER_BLOCK 4

// One wave (64 lanes) per row n:
//   phase 1: h = x[n] @ W^T + b  (lane d computes h[d]); z = h / max(||h||, eps)
//   phase 2: stream 20 protos of out_proto[uidx[n]] as coalesced float4,
//            per-16-lane-group reduction of ||a||^2 and a.z, accumulate cos, sum.
__global__ __launch_bounds__(256) void user_memory_fused(
    const int*   __restrict__ uidx,
    const float* __restrict__ x,
    const float* __restrict__ proto,
    const float* __restrict__ W,
    const float* __restrict__ bias,
    float*       __restrict__ out,
    int n_rows)
{
    __shared__ __align__(16) float x_lds[ROWS_PER_BLOCK][D];
    __shared__ __align__(16) float z_lds[ROWS_PER_BLOCK][D];

    const int wave = threadIdx.x >> 6;
    const int lane = threadIdx.x & 63;
    const int row  = blockIdx.x * ROWS_PER_BLOCK + wave;
    if (row >= n_rows) return;   // grid is exact for N % 4 == 0

    // ---- phase 1: h[lane] = b[lane] + sum_k x[row][k] * W[lane][k] ----
    x_lds[wave][lane] = x[row * D + lane];
    __syncthreads();

    float acc = bias[lane];
    const float4* wrow = (const float4*)(W + lane * D);      // per-lane contiguous, L1-hot
    const float4* xr   = (const float4*)(x_lds[wave]);       // broadcast reads
#pragma unroll
    for (int k = 0; k < D / 4; ++k) {
        float4 wv = wrow[k];
        float4 xk = xr[k];
        acc += wv.x * xk.x + wv.y * xk.y + wv.z * xk.z + wv.w * xk.w;
    }

    // ||h||^2 across the wave (xor butterfly, result broadcast to all lanes)
    float s = acc * acc;
#pragma unroll
    for (int off = 32; off >= 1; off >>= 1) s += __shfl_xor(s, off);
    float rn = 1.0f / fmaxf(sqrtf(s), 1e-12f);
    z_lds[wave][lane] = acc * rn;
    __syncthreads();

    // ---- phase 2: gather + normalize + dot over 20 protos ----
    const int u = uidx[row];
    const float4* ap = (const float4*)(proto + (size_t)u * (P * D));

    const int dq = lane & 15;                 // which quarter of d-range this lane covers
    // z elements 4*dq .. 4*dq+3 (lanes 16 apart read same LDS addr -> broadcast)
    const float4 zv = ((const float4*)(z_lds[wave]))[dq];

    float cacc = 0.0f;
#pragma unroll
    for (int it = 0; it < 5; ++it) {
        // wave reads 64 * 16B = 1024B = 4 protos; lane covers proto (lane>>4),
        // elements 4*(lane&15) .. +3 of that proto
        float4 av = ap[it * 64 + lane];
        float s2 = av.x * av.x + av.y * av.y + av.z * av.z + av.w * av.w;
        float dt = av.x * zv.x + av.y * zv.y + av.z * zv.z + av.w * zv.w;
#pragma unroll
        for (int off = 1; off <= 8; off <<= 1) {
            s2 += __shfl_xor(s2, off);
            dt += __shfl_xor(dt, off);
        }
        // cos = dt / max(sqrt(s2), 1e-12) == dt * rsqrt(max(s2, 1e-24))
        cacc += dt * __frsqrt_rn(fmaxf(s2, 1e-24f));
    }

    // each 16-lane group holds an identical partial; xor 16 & 32 combines the
    // four groups exactly once each
    cacc += __shfl_xor(cacc, 16);
    cacc += __shfl_xor(cacc, 32);
    if (lane == 0) out[row] = cacc;
}

extern "C" void kernel_launch(void* const* d_in, const int* in_sizes, int n_in,
                              void* d_out, int out_size, void* d_ws, size_t ws_size,
                              hipStream_t stream) {
    const int*   uidx  = (const int*)d_in[0];
    const float* x     = (const float*)d_in[1];
    const float* proto = (const float*)d_in[2];
    const float* W     = (const float*)d_in[3];
    const float* bias  = (const float*)d_in[4];
    float*       out   = (float*)d_out;

    const int n = in_sizes[0];
    const int blocks = (n + ROWS_PER_BLOCK - 1) / ROWS_PER_BLOCK;
    hipLaunchKernelGGL(user_memory_fused, dim3(blocks), dim3(256), 0, stream,
                       uidx, x, proto, W, bias, out, n);
}

// Round 2
// 582.136 us; speedup vs baseline: 1.0000x; 1.0000x over previous
//
#include <hip/hip_runtime.h>
#include <hip/hip_bf16.h>

#define D 64
#define P 20            // NUM_PROTO
#define ROWS_PER_BLOCK 4

// One wave (64 lanes) per row n.
// Gather loads (HBM-heavy) are issued FIRST so the ~900-cyc miss latency
// overlaps the phase-1 matvec; z never round-trips through LDS.
__global__ __launch_bounds__(256) void user_memory_fused(
    const int*   __restrict__ uidx,
    const float* __restrict__ x,
    const float* __restrict__ proto,
    const float* __restrict__ W,
    const float* __restrict__ bias,
    float*       __restrict__ out,
    int n_rows)
{
    __shared__ __align__(16) float x_lds[ROWS_PER_BLOCK][D];

    const int wave = threadIdx.x >> 6;
    const int lane = threadIdx.x & 63;
    const int row  = blockIdx.x * ROWS_PER_BLOCK + wave;
    if (row >= n_rows) return;   // exact for N % ROWS_PER_BLOCK == 0

    // ---- issue the anchor gather immediately (depends only on uidx) ----
    const int u = uidx[row];
    const float4* ap = (const float4*)(proto + (size_t)u * (P * D)) + lane;
    float4 av0 = ap[0];      // wave reads 5 x 1KiB, fully coalesced
    float4 av1 = ap[64];
    float4 av2 = ap[128];
    float4 av3 = ap[192];
    float4 av4 = ap[256];

    // ---- stage x row in LDS (float4 x 16 lanes), then matvec ----
    if (lane < 16)
        ((float4*)x_lds[wave])[lane] = ((const float4*)(x + (size_t)row * D))[lane];
    __syncthreads();

    float acc = bias[lane];
    const float4* wrow = (const float4*)(W + lane * D);   // per-lane contiguous, L1-hot
    const float4* xr   = (const float4*)(x_lds[wave]);    // broadcast reads
#pragma unroll
    for (int k = 0; k < D / 4; ++k) {
        float4 wv = wrow[k];
        float4 xk = xr[k];
        acc += wv.x * xk.x + wv.y * xk.y + wv.z * xk.z + wv.w * xk.w;
    }

    // ||h||^2 across the wave; z[lane] stays in-register
    float s = acc * acc;
#pragma unroll
    for (int off = 32; off >= 1; off >>= 1) s += __shfl_xor(s, off);
    float z = acc * (1.0f / fmaxf(sqrtf(s), 1e-12f));

    // lane needs z[4*(lane&15) .. +3] — 4 bpermute shuffles, no LDS/barrier
    const int zb = (lane & 15) * 4;
    float4 zv;
    zv.x = __shfl(z, zb + 0);
    zv.y = __shfl(z, zb + 1);
    zv.z = __shfl(z, zb + 2);
    zv.w = __shfl(z, zb + 3);

    // ---- consume prefetched anchors: normalize + dot over 20 protos ----
    float cacc = 0.0f;
    float4 avs[5] = {av0, av1, av2, av3, av4};
#pragma unroll
    for (int it = 0; it < 5; ++it) {
        float4 av = avs[it];
        float s2 = av.x * av.x + av.y * av.y + av.z * av.z + av.w * av.w;
        float dt = av.x * zv.x + av.y * zv.y + av.z * zv.z + av.w * zv.w;
#pragma unroll
        for (int off = 1; off <= 8; off <<= 1) {
            s2 += __shfl_xor(s2, off);
            dt += __shfl_xor(dt, off);
        }
        cacc += dt * __frsqrt_rn(fmaxf(s2, 1e-24f));   // dt / max(||a||, 1e-12)
    }

    // four 16-lane groups hold identical partials; xor 16 & 32 combine them once each
    cacc += __shfl_xor(cacc, 16);
    cacc += __shfl_xor(cacc, 32);
    if (lane == 0) out[row] = cacc;
}

extern "C" void kernel_launch(void* const* d_in, const int* in_sizes, int n_in,
                              void* d_out, int out_size, void* d_ws, size_t ws_size,
                              hipStream_t stream) {
    const int*   uidx  = (const int*)d_in[0];
    const float* x     = (const float*)d_in[1];
    const float* proto = (const float*)d_in[2];
    const float* W     = (const float*)d_in[3];
    const float* bias  = (const float*)d_in[4];
    float*       out   = (float*)d_out;

    const int n = in_sizes[0];
    const int blocks = (n + ROWS_PER_BLOCK - 1) / ROWS_PER_BLOCK;
    hipLaunchKernelGGL(user_memory_fused, dim3(blocks), dim3(256), 0, stream,
                       uidx, x, proto, W, bias, out, n);
}